// Round 6
// baseline (404.238 us; speedup 1.0000x reference)
//
#include <hip/hip_runtime.h>
#include <math.h>

// LinearAutoregressiveHMM fused kernel for MI355X (gfx950).
// B=8192, L=64, C=4, K=8, P=16.
// Block = 256 threads (4 waves); each wave owns 2 batch rows; 8 rows/block.
//
// R6 changes vs R5 (250us, VALUBusy 39% -> stall-bound):
//  - Diagnosis: W via s_load shares lgkmcnt with ds_read x, SMEM is
//    out-of-order -> compiler emits lgkmcnt(0) full drains every j.
//    (History: R1 paid AGPR round-trips, R2/R3 scratch, R4 DS-pipe W.)
//  - Fix: W loads forced to VECTOR global loads (opaque v_mov 0 taint so
//    they can't scalarize): uniform address = broadcast L1 hit, tracked by
//    vmcnt (independent counter) -> x ds_reads and W loads both pipeline.
//    Per-CU per j: 128 VALU cyc vs ~96 DS vs ~64 VMEM -> VALU-bound.
//  - Phase C: p-loop fully unrolled + W prefetched one step ahead (states
//    known after Phase B; only x is serial). Numerics unchanged.
//  - Phase B unchanged from R5 (passed, conflicts down).

namespace {
constexpr int BB   = 8192;
constexpr int LL   = 64;
constexpr int CCH  = 4;
constexpr int KK   = 8;
constexpr int PP   = 16;
constexpr int BPB  = 8;    // batch rows per block
constexpr int NTHR = 256;
}

__global__ __launch_bounds__(256)
void lahmm_fused(const float* __restrict__ em,  const float* __restrict__ trm,
                 const float* __restrict__ ini, const float* __restrict__ mns,
                 const float* __restrict__ cvc, const float* __restrict__ Wg,
                 float* __restrict__ out)
{
    __shared__ __align__(16) float sBuf[BPB][576];     // per b: 144 timesteps x 4 ch (18KB)
    __shared__ __align__(16) float sElp[LL][BPB][KK];  // [t][b][k] full (16KB)
    __shared__ float sLT[KK][KK];      // log(softmax(trans)+1e-8), [j][k]
    __shared__ float sLI[KK];          // log(softmax(init))
    __shared__ float sMean[KK][CCH];
    __shared__ float sVar[KK][CCH];
    __shared__ float sLogdet[KK];
    __shared__ int   sNs[KK];          // argmax of each trans row
    __shared__ int   sStateB[BPB];     // per-b argmax state after recursion
    __shared__ unsigned char sChain[KK][PP];  // state chain from each start state

    const int tid   = threadIdx.x;
    const int lane  = tid & 63;
    const int wv    = tid >> 6;
    const int bBase = blockIdx.x * BPB;

    // Opaque zero in a VGPR: tainting W indices with this forces the
    // compiler to keep W loads on the VECTOR memory path (vmcnt), so they
    // never mix with ds_read's lgkmcnt and never scalarize to SMEM.
    int vzero;
    asm volatile("v_mov_b32 %0, 0" : "=v"(vzero));

    // ---------------- Phase 0: stage emissions + small tables ----------------
    const float4* em4 = reinterpret_cast<const float4*>(em);
    float4* sBuf4 = reinterpret_cast<float4*>(&sBuf[0][0]);
#pragma unroll
    for (int r = 0; r < 2; ++r) {
        int idx = tid + r * 256;            // 0..511 covers 8 b x 64 rows
        int bl = idx >> 6, row = idx & 63;
        sBuf4[bl * 144 + 64 + row] = em4[(bBase + bl) * 64 + row];
        sBuf4[bl * 144 + row]      = make_float4(0.f, 0.f, 0.f, 0.f);
    }

    if (tid < KK) {
        float row[KK];
        float m = -INFINITY;
#pragma unroll
        for (int k = 0; k < KK; ++k) { row[k] = trm[tid * KK + k]; m = fmaxf(m, row[k]); }
        float se = 0.f;
#pragma unroll
        for (int k = 0; k < KK; ++k) se += expf(row[k] - m);
        int best = 0; float bv = row[0];
#pragma unroll
        for (int k = 1; k < KK; ++k) if (row[k] > bv) { bv = row[k]; best = k; }
        sNs[tid] = best;
#pragma unroll
        for (int k = 0; k < KK; ++k) sLT[tid][k] = logf(expf(row[k] - m) / se + 1e-8f);
    } else if (tid == 8) {
        float x[KK]; float m = -INFINITY;
#pragma unroll
        for (int k = 0; k < KK; ++k) { x[k] = ini[k]; m = fmaxf(m, x[k]); }
        float se = 0.f;
#pragma unroll
        for (int k = 0; k < KK; ++k) se += expf(x[k] - m);
#pragma unroll
        for (int k = 0; k < KK; ++k) sLI[k] = logf(expf(x[k] - m) / se);
    } else if (tid >= 32 && tid < 64) {
        int i = tid - 32;                   // 0..31 covers K*C
        (&sMean[0][0])[i] = mns[i];
        (&sVar[0][0])[i]  = expf(cvc[i]) + 1e-6f;
    }
    __syncthreads();
    if (tid < KK) {
        float ld = 0.f;
#pragma unroll
        for (int c = 0; c < CCH; ++c) ld += logf(sVar[tid][c]);
        sLogdet[tid] = ld;
        int s = tid;
#pragma unroll
        for (int p = 0; p < PP; ++p) { s = sNs[s]; sChain[tid][p] = (unsigned char)s; }
    }
    __syncthreads();

    // ---------------- Phase A: AR scores (the 8.6 GFLOP conv) ----------------
    // 4 k-quarter passes (16 live accs). W via forced-VMEM uniform loads.
    const int b0l = wv * 2, b1l = wv * 2 + 1;
    const float4* bv0 = reinterpret_cast<const float4*>(&sBuf[b0l][0]);
    const float4* bv1 = reinterpret_cast<const float4*>(&sBuf[b1l][0]);
    const float4* Wvec = reinterpret_cast<const float4*>(Wg) + vzero;  // VGPR-tainted base
    const int t = lane;   // lane owns output timestep t for both its b's

    float e0[KK], e1[KK];
    const float c2pi = 7.3515082656373819f;   // C * log(2*pi)

#pragma unroll
    for (int kq = 0; kq < 4; ++kq) {
        float acc0[2][CCH], acc1[2][CCH];
#pragma unroll
        for (int q = 0; q < 2; ++q)
#pragma unroll
            for (int c = 0; c < CCH; ++c) { acc0[q][c] = 0.f; acc1[q][c] = 0.f; }

#pragma unroll 2
        for (int j = 1; j < LL; ++j) {      // j=0 multiplies only the zero pad
            float4 x0 = bv0[t + j];         // per-lane contiguous b128 (lgkmcnt)
            float4 x1 = bv1[t + j];
#pragma unroll
            for (int q = 0; q < 2; ++q) {
#pragma unroll
                for (int c = 0; c < CCH; ++c) {
                    // uniform addr + opaque taint -> global_load (vmcnt), L1 broadcast
                    float4 w = Wvec[((kq * 2 + q) * CCH + c) * LL + j];
                    float a0 = acc0[q][c], a1 = acc1[q][c];
                    a0 = fmaf(x0.x, w.x, a0); a1 = fmaf(x1.x, w.x, a1);
                    a0 = fmaf(x0.y, w.y, a0); a1 = fmaf(x1.y, w.y, a1);
                    a0 = fmaf(x0.z, w.z, a0); a1 = fmaf(x1.z, w.z, a1);
                    a0 = fmaf(x0.w, w.w, a0); a1 = fmaf(x1.w, w.w, a1);
                    acc0[q][c] = a0; acc1[q][c] = a1;
                }
            }
        }

        // emission log-probs for this k-quarter (numerics identical to R1-R5)
        float4 tg0 = bv0[64 + t], tg1 = bv1[64 + t];
#pragma unroll
        for (int q = 0; q < 2; ++q) {
            const int k = kq * 2 + q;       // compile-time (kq unrolled)
            float mh0 = 0.f, mh1 = 0.f;
#pragma unroll
            for (int c = 0; c < CCH; ++c) {
                float mu = sMean[k][c], va = sVar[k][c];
                float g0 = (c == 0) ? tg0.x : (c == 1) ? tg0.y : (c == 2) ? tg0.z : tg0.w;
                float g1 = (c == 0) ? tg1.x : (c == 1) ? tg1.y : (c == 2) ? tg1.z : tg1.w;
                float d0 = g0 - (mu + acc0[q][c]);
                float d1 = g1 - (mu + acc1[q][c]);
                mh0 += d0 * d0 / va;
                mh1 += d1 * d1 / va;
            }
            e0[k] = -0.5f * (mh0 + sLogdet[k] + c2pi);
            e1[k] = -0.5f * (mh1 + sLogdet[k] + c2pi);
        }
    }

    // store elp to full [t][b][k] staging
    {
        float4* d0 = reinterpret_cast<float4*>(&sElp[t][b0l][0]);
        d0[0] = make_float4(e0[0], e0[1], e0[2], e0[3]);
        d0[1] = make_float4(e0[4], e0[5], e0[6], e0[7]);
        float4* d1 = reinterpret_cast<float4*>(&sElp[t][b1l][0]);
        d1[0] = make_float4(e1[0], e1[1], e1[2], e1[3]);
        d1[1] = make_float4(e1[4], e1[5], e1[6], e1[7]);
    }
    __syncthreads();

    // ---------------- Phase B: HMM forward recursion (wave 0 only) ----------------
    // lane = (b,k). Same balanced-tree max/sum association as passing rounds.
    if (wv == 0) {
        const int bb = lane >> 3, kb = lane & 7;
        const int gbase = lane & 0x38;      // lane of (bb, j=0)
        float ltT[KK];
#pragma unroll
        for (int j = 0; j < KK; ++j) ltT[j] = sLT[j][kb];
        float la = sLI[kb] + sElp[0][bb][kb];
        for (int ts = 1; ts < LL; ++ts) {
            float v0 = __shfl(la, gbase + 0) + ltT[0];
            float v1 = __shfl(la, gbase + 1) + ltT[1];
            float v2 = __shfl(la, gbase + 2) + ltT[2];
            float v3 = __shfl(la, gbase + 3) + ltT[3];
            float v4 = __shfl(la, gbase + 4) + ltT[4];
            float v5 = __shfl(la, gbase + 5) + ltT[5];
            float v6 = __shfl(la, gbase + 6) + ltT[6];
            float v7 = __shfl(la, gbase + 7) + ltT[7];
            float m = fmaxf(fmaxf(fmaxf(v0, v1), fmaxf(v2, v3)),
                            fmaxf(fmaxf(v4, v5), fmaxf(v6, v7)));
            float s = (expf(v0 - m) + expf(v1 - m)) + (expf(v2 - m) + expf(v3 - m))
                    + ((expf(v4 - m) + expf(v5 - m)) + (expf(v6 - m) + expf(v7 - m)));
            la = m + logf(s) + sElp[ts][bb][kb];
        }
        float bv = la; int bi = kb;
#pragma unroll
        for (int d = 1; d < 8; d <<= 1) {
            float ov = __shfl_xor(bv, d);
            int   oi = __shfl_xor(bi, d);
            if (ov > bv || (ov == bv && oi < bi)) { bv = ov; bi = oi; }
        }
        if (kb == 0) sStateB[bb] = bi;
    }
    __syncthreads();

    // ---------------- Phase C: P-step rollout (unrolled, W prefetched) ----------------
    const int s00 = sStateB[b0l];
    const int s01 = sStateB[b1l];
    float* bf0 = &sBuf[b0l][0];
    float* bf1 = &sBuf[b1l][0];

    float4 cw0[CCH], cw1[CCH];              // current-step W rows
    {
        int sa = (int)sChain[s00][0], sb = (int)sChain[s01][0];
#pragma unroll
        for (int c = 0; c < CCH; ++c) {
            cw0[c] = Wvec[(sa * CCH + c) * LL + t];
            cw1[c] = Wvec[(sb * CCH + c) * LL + t];
        }
    }
#pragma unroll
    for (int p = 0; p < PP; ++p) {
        int sa = (int)sChain[s00][p];
        int sb = (int)sChain[s01][p];
        float4 nw0[CCH], nw1[CCH];
        if (p + 1 < PP) {                   // issue next step's W early (vmcnt in flight)
            int na = (int)sChain[s00][p + 1], nb = (int)sChain[s01][p + 1];
#pragma unroll
            for (int c = 0; c < CCH; ++c) {
                nw0[c] = Wvec[(na * CCH + c) * LL + t];
                nw1[c] = Wvec[(nb * CCH + c) * LL + t];
            }
        }
        float4 x0 = bv0[64 + p + t];        // window [p, p+63] of rolling buffer
        float4 x1 = bv1[64 + p + t];
        float pr0[CCH], pr1[CCH];
#pragma unroll
        for (int c = 0; c < CCH; ++c) {
            pr0[c] = fmaf(x0.w, cw0[c].w, fmaf(x0.z, cw0[c].z,
                     fmaf(x0.y, cw0[c].y, x0.x * cw0[c].x)));
            pr1[c] = fmaf(x1.w, cw1[c].w, fmaf(x1.z, cw1[c].z,
                     fmaf(x1.y, cw1[c].y, x1.x * cw1[c].x)));
        }
#pragma unroll
        for (int c = 0; c < CCH; ++c) {
#pragma unroll
            for (int d = 1; d < 64; d <<= 1) {
                pr0[c] += __shfl_xor(pr0[c], d);
                pr1[c] += __shfl_xor(pr1[c], d);
            }
            pr0[c] += sMean[sa][c];
            pr1[c] += sMean[sb][c];
        }
        int cw = lane & 3;
        float v0 = (cw == 0) ? pr0[0] : (cw == 1) ? pr0[1] : (cw == 2) ? pr0[2] : pr0[3];
        float v1 = (cw == 0) ? pr1[0] : (cw == 1) ? pr1[1] : (cw == 2) ? pr1[2] : pr1[3];
        if (lane < 4) {
            bf0[(128 + p) * 4 + cw] = v0;                       // append pred to buffer
            out[(bBase + b0l) * (PP * CCH) + p * CCH + cw] = v0;
        } else if (lane < 8) {
            bf1[(128 + p) * 4 + cw] = v1;
            out[(bBase + b1l) * (PP * CCH) + p * CCH + cw] = v1;
        }
        __syncthreads();
        if (p + 1 < PP) {
#pragma unroll
            for (int c = 0; c < CCH; ++c) { cw0[c] = nw0[c]; cw1[c] = nw1[c]; }
        }
    }
}

extern "C" void kernel_launch(void* const* d_in, const int* in_sizes, int n_in,
                              void* d_out, int out_size, void* d_ws, size_t ws_size,
                              hipStream_t stream) {
    (void)in_sizes; (void)n_in; (void)d_ws; (void)ws_size; (void)out_size;
    const float* em  = (const float*)d_in[0];
    const float* trm = (const float*)d_in[1];
    const float* ini = (const float*)d_in[2];
    const float* mns = (const float*)d_in[3];
    const float* cvc = (const float*)d_in[4];
    const float* Wg  = (const float*)d_in[5];
    float* out = (float*)d_out;
    dim3 grid(BB / BPB), block(NTHR);
    hipLaunchKernelGGL(lahmm_fused, grid, block, 0, stream,
                       em, trm, ini, mns, cvc, Wg, out);
}

// Round 7
// 253.268 us; speedup vs baseline: 1.5961x; 1.5961x over previous
//
#include <hip/hip_runtime.h>
#include <math.h>

// LinearAutoregressiveHMM fused kernel for MI355X (gfx950).
// B=8192, L=64, C=4, K=8, P=16.
// Block = 256 threads (4 waves); each wave owns 2 batch rows; 8 rows/block.
//
// R7 changes vs R6 (377us, forced-VMEM W regressed):
//  - Evidence across rounds: scalarized s_load W is the best W path
//    (R2=205 even WITH spills); k-halves beat k-quarters (drain amortized
//    over 256 VALU-cy; half the x ds_reads and loop overhead).
//  - So: R2 structure (k-halves, 32 accs) at the current register regime
//    (plain launch_bounds(256) grants 84-100 VGPRs -> no spills).
//  - NEW: prologue kernel transposes W into d_ws as Wt[j][k][c][c']:
//    for each j one k-half is 256B CONTIGUOUS -> few wide s_load_dwordx16
//    instead of 16 strided dwordx4 chains (fewer SGPRs, fewer lgkm events
//    per drain, K$ streaming).
//  - Phases B/C byte-identical to R5 (passed 2x).

namespace {
constexpr int BB   = 8192;
constexpr int LL   = 64;
constexpr int CCH  = 4;
constexpr int KK   = 8;
constexpr int PP   = 16;
constexpr int BPB  = 8;    // batch rows per block
constexpr int NTHR = 256;
}

// Wt[j][k][c][c'] <- W[k][c][j][c']  (2048 float4 moves)
__global__ void lahmm_transposeW(const float* __restrict__ Wg, float* __restrict__ Wt) {
    int m = blockIdx.x * 256 + threadIdx.x;       // float4 index over 2048
    int j = m >> 5, kc = m & 31;
    reinterpret_cast<float4*>(Wt)[m] =
        reinterpret_cast<const float4*>(Wg)[kc * 64 + j];
}

__global__ __launch_bounds__(256)
void lahmm_fused(const float* __restrict__ em,  const float* __restrict__ trm,
                 const float* __restrict__ ini, const float* __restrict__ mns,
                 const float* __restrict__ cvc, const float* __restrict__ Wg,
                 const float* __restrict__ Wt,  float* __restrict__ out)
{
    __shared__ __align__(16) float sBuf[BPB][576];     // per b: 144 timesteps x 4 ch (18KB)
    __shared__ __align__(16) float sElp[LL][BPB][KK];  // [t][b][k] full (16KB)
    __shared__ float sLT[KK][KK];      // log(softmax(trans)+1e-8), [j][k]
    __shared__ float sLI[KK];          // log(softmax(init))
    __shared__ float sMean[KK][CCH];
    __shared__ float sVar[KK][CCH];
    __shared__ float sLogdet[KK];
    __shared__ int   sNs[KK];          // argmax of each trans row
    __shared__ int   sStateB[BPB];     // per-b argmax state after recursion
    __shared__ unsigned char sChain[KK][PP];  // state chain from each start state

    const int tid   = threadIdx.x;
    const int lane  = tid & 63;
    const int wv    = tid >> 6;
    const int bBase = blockIdx.x * BPB;

    // ---------------- Phase 0: stage emissions + small tables ----------------
    const float4* em4 = reinterpret_cast<const float4*>(em);
    float4* sBuf4 = reinterpret_cast<float4*>(&sBuf[0][0]);
#pragma unroll
    for (int r = 0; r < 2; ++r) {
        int idx = tid + r * 256;            // 0..511 covers 8 b x 64 rows
        int bl = idx >> 6, row = idx & 63;
        sBuf4[bl * 144 + 64 + row] = em4[(bBase + bl) * 64 + row];
        sBuf4[bl * 144 + row]      = make_float4(0.f, 0.f, 0.f, 0.f);
    }

    if (tid < KK) {
        float row[KK];
        float m = -INFINITY;
#pragma unroll
        for (int k = 0; k < KK; ++k) { row[k] = trm[tid * KK + k]; m = fmaxf(m, row[k]); }
        float se = 0.f;
#pragma unroll
        for (int k = 0; k < KK; ++k) se += expf(row[k] - m);
        int best = 0; float bv = row[0];
#pragma unroll
        for (int k = 1; k < KK; ++k) if (row[k] > bv) { bv = row[k]; best = k; }
        sNs[tid] = best;
#pragma unroll
        for (int k = 0; k < KK; ++k) sLT[tid][k] = logf(expf(row[k] - m) / se + 1e-8f);
    } else if (tid == 8) {
        float x[KK]; float m = -INFINITY;
#pragma unroll
        for (int k = 0; k < KK; ++k) { x[k] = ini[k]; m = fmaxf(m, x[k]); }
        float se = 0.f;
#pragma unroll
        for (int k = 0; k < KK; ++k) se += expf(x[k] - m);
#pragma unroll
        for (int k = 0; k < KK; ++k) sLI[k] = logf(expf(x[k] - m) / se);
    } else if (tid >= 32 && tid < 64) {
        int i = tid - 32;                   // 0..31 covers K*C
        (&sMean[0][0])[i] = mns[i];
        (&sVar[0][0])[i]  = expf(cvc[i]) + 1e-6f;
    }
    __syncthreads();
    if (tid < KK) {
        float ld = 0.f;
#pragma unroll
        for (int c = 0; c < CCH; ++c) ld += logf(sVar[tid][c]);
        sLogdet[tid] = ld;
        int s = tid;
#pragma unroll
        for (int p = 0; p < PP; ++p) { s = sNs[s]; sChain[tid][p] = (unsigned char)s; }
    }
    __syncthreads();

    // ---------------- Phase A: AR scores (the 8.6 GFLOP conv) ----------------
    // 2 k-half passes (32 live accs, fits the ~100-VGPR grant). W from the
    // j-major transposed buffer: per j one half = 256B contiguous -> wide
    // scalar loads on the (idle) scalar pipe.
    const int b0l = wv * 2, b1l = wv * 2 + 1;
    const float4* bv0 = reinterpret_cast<const float4*>(&sBuf[b0l][0]);
    const float4* bv1 = reinterpret_cast<const float4*>(&sBuf[b1l][0]);
    const float4* Wt4 = reinterpret_cast<const float4*>(Wt);   // [j][kc]
    const int t = lane;   // lane owns output timestep t for both its b's

    float e0[KK], e1[KK];
    const float c2pi = 7.3515082656373819f;   // C * log(2*pi)

#pragma unroll
    for (int kh = 0; kh < 2; ++kh) {
        float acc0[4][CCH], acc1[4][CCH];
#pragma unroll
        for (int q = 0; q < 4; ++q)
#pragma unroll
            for (int c = 0; c < CCH; ++c) { acc0[q][c] = 0.f; acc1[q][c] = 0.f; }

#pragma unroll 2
        for (int j = 1; j < LL; ++j) {      // j=0 multiplies only the zero pad
            float4 x0 = bv0[t + j];         // per-lane contiguous b128 (lgkmcnt/DS)
            float4 x1 = bv1[t + j];
#pragma unroll
            for (int q = 0; q < 4; ++q) {
#pragma unroll
                for (int c = 0; c < CCH; ++c) {
                    // uniform + contiguous across (q,c) -> s_load_dwordx16 clusters
                    float4 w = Wt4[j * 32 + (kh * 4 + q) * CCH + c];
                    float a0 = acc0[q][c], a1 = acc1[q][c];
                    a0 = fmaf(x0.x, w.x, a0); a1 = fmaf(x1.x, w.x, a1);
                    a0 = fmaf(x0.y, w.y, a0); a1 = fmaf(x1.y, w.y, a1);
                    a0 = fmaf(x0.z, w.z, a0); a1 = fmaf(x1.z, w.z, a1);
                    a0 = fmaf(x0.w, w.w, a0); a1 = fmaf(x1.w, w.w, a1);
                    acc0[q][c] = a0; acc1[q][c] = a1;
                }
            }
        }

        // emission log-probs for this k-half (numerics identical to R1-R6)
        float4 tg0 = bv0[64 + t], tg1 = bv1[64 + t];
#pragma unroll
        for (int q = 0; q < 4; ++q) {
            const int k = kh * 4 + q;       // compile-time (kh,q unrolled)
            float mh0 = 0.f, mh1 = 0.f;
#pragma unroll
            for (int c = 0; c < CCH; ++c) {
                float mu = sMean[k][c], va = sVar[k][c];
                float g0 = (c == 0) ? tg0.x : (c == 1) ? tg0.y : (c == 2) ? tg0.z : tg0.w;
                float g1 = (c == 0) ? tg1.x : (c == 1) ? tg1.y : (c == 2) ? tg1.z : tg1.w;
                float d0 = g0 - (mu + acc0[q][c]);
                float d1 = g1 - (mu + acc1[q][c]);
                mh0 += d0 * d0 / va;
                mh1 += d1 * d1 / va;
            }
            e0[k] = -0.5f * (mh0 + sLogdet[k] + c2pi);
            e1[k] = -0.5f * (mh1 + sLogdet[k] + c2pi);
        }
    }

    // store elp to full [t][b][k] staging
    {
        float4* d0 = reinterpret_cast<float4*>(&sElp[t][b0l][0]);
        d0[0] = make_float4(e0[0], e0[1], e0[2], e0[3]);
        d0[1] = make_float4(e0[4], e0[5], e0[6], e0[7]);
        float4* d1 = reinterpret_cast<float4*>(&sElp[t][b1l][0]);
        d1[0] = make_float4(e1[0], e1[1], e1[2], e1[3]);
        d1[1] = make_float4(e1[4], e1[5], e1[6], e1[7]);
    }
    __syncthreads();

    // ---------------- Phase B: HMM forward recursion (wave 0 only) ----------------
    // lane = (b,k). Same balanced-tree max/sum association as passing rounds.
    if (wv == 0) {
        const int bb = lane >> 3, kb = lane & 7;
        const int gbase = lane & 0x38;      // lane of (bb, j=0)
        float ltT[KK];
#pragma unroll
        for (int j = 0; j < KK; ++j) ltT[j] = sLT[j][kb];
        float la = sLI[kb] + sElp[0][bb][kb];
        for (int ts = 1; ts < LL; ++ts) {
            float v0 = __shfl(la, gbase + 0) + ltT[0];
            float v1 = __shfl(la, gbase + 1) + ltT[1];
            float v2 = __shfl(la, gbase + 2) + ltT[2];
            float v3 = __shfl(la, gbase + 3) + ltT[3];
            float v4 = __shfl(la, gbase + 4) + ltT[4];
            float v5 = __shfl(la, gbase + 5) + ltT[5];
            float v6 = __shfl(la, gbase + 6) + ltT[6];
            float v7 = __shfl(la, gbase + 7) + ltT[7];
            float m = fmaxf(fmaxf(fmaxf(v0, v1), fmaxf(v2, v3)),
                            fmaxf(fmaxf(v4, v5), fmaxf(v6, v7)));
            float s = (expf(v0 - m) + expf(v1 - m)) + (expf(v2 - m) + expf(v3 - m))
                    + ((expf(v4 - m) + expf(v5 - m)) + (expf(v6 - m) + expf(v7 - m)));
            la = m + logf(s) + sElp[ts][bb][kb];
        }
        float bv = la; int bi = kb;
#pragma unroll
        for (int d = 1; d < 8; d <<= 1) {
            float ov = __shfl_xor(bv, d);
            int   oi = __shfl_xor(bi, d);
            if (ov > bv || (ov == bv && oi < bi)) { bv = ov; bi = oi; }
        }
        if (kb == 0) sStateB[bb] = bi;
    }
    __syncthreads();

    // ---------------- Phase C: P-step autoregressive rollout ----------------
    const int s00 = sStateB[b0l];
    const int s01 = sStateB[b1l];
    const float4* Wv = reinterpret_cast<const float4*>(Wg);   // per-lane coalesced, L2-hot
    float* bf0 = &sBuf[b0l][0];
    float* bf1 = &sBuf[b1l][0];
    for (int p = 0; p < PP; ++p) {
        int sa = (int)sChain[s00][p];
        int sb = (int)sChain[s01][p];
        float4 x0 = bv0[64 + p + t];       // window [p, p+63] of rolling buffer
        float4 x1 = bv1[64 + p + t];
        float pr0[CCH], pr1[CCH];
#pragma unroll
        for (int c = 0; c < CCH; ++c) {
            float4 w0 = Wv[(sa * CCH + c) * LL + t];
            float4 w1 = Wv[(sb * CCH + c) * LL + t];
            pr0[c] = fmaf(x0.w, w0.w, fmaf(x0.z, w0.z, fmaf(x0.y, w0.y, x0.x * w0.x)));
            pr1[c] = fmaf(x1.w, w1.w, fmaf(x1.z, w1.z, fmaf(x1.y, w1.y, x1.x * w1.x)));
        }
#pragma unroll
        for (int c = 0; c < CCH; ++c) {
#pragma unroll
            for (int d = 1; d < 64; d <<= 1) {
                pr0[c] += __shfl_xor(pr0[c], d);
                pr1[c] += __shfl_xor(pr1[c], d);
            }
            pr0[c] += sMean[sa][c];
            pr1[c] += sMean[sb][c];
        }
        int cw = lane & 3;
        float v0 = (cw == 0) ? pr0[0] : (cw == 1) ? pr0[1] : (cw == 2) ? pr0[2] : pr0[3];
        float v1 = (cw == 0) ? pr1[0] : (cw == 1) ? pr1[1] : (cw == 2) ? pr1[2] : pr1[3];
        if (lane < 4) {
            bf0[(128 + p) * 4 + cw] = v0;                       // append pred to buffer
            out[(bBase + b0l) * (PP * CCH) + p * CCH + cw] = v0;
        } else if (lane < 8) {
            bf1[(128 + p) * 4 + cw] = v1;
            out[(bBase + b1l) * (PP * CCH) + p * CCH + cw] = v1;
        }
        __syncthreads();
    }
}

extern "C" void kernel_launch(void* const* d_in, const int* in_sizes, int n_in,
                              void* d_out, int out_size, void* d_ws, size_t ws_size,
                              hipStream_t stream) {
    (void)in_sizes; (void)n_in; (void)ws_size; (void)out_size;
    const float* em  = (const float*)d_in[0];
    const float* trm = (const float*)d_in[1];
    const float* ini = (const float*)d_in[2];
    const float* mns = (const float*)d_in[3];
    const float* cvc = (const float*)d_in[4];
    const float* Wg  = (const float*)d_in[5];
    float* out = (float*)d_out;
    float* Wt  = (float*)d_ws;                    // 32KB scratch for transposed W

    hipLaunchKernelGGL(lahmm_transposeW, dim3(8), dim3(256), 0, stream, Wg, Wt);
    hipLaunchKernelGGL(lahmm_fused, dim3(BB / BPB), dim3(NTHR), 0, stream,
                       em, trm, ini, mns, cvc, Wg, Wt, out);
}